// Round 5
// baseline (142.213 us; speedup 1.0000x reference)
//
#include <hip/hip_runtime.h>

// Problem constants (match reference)
constexpr int B        = 65536;
constexpr int N_SPARSE = 20;
constexpr int N_VARLEN = 3;
constexpr int SEQ_LEN  = 50;
constexpr int VOCAB    = 100000;
constexpr int N_DENSE  = 13;
constexpr int VAR_TOT  = N_VARLEN * SEQ_LEN;   // 150

constexpr int NPAIR = B / 2;                   // 32768 row-pairs
constexpr int NBLK  = NPAIR * 16 / 256;        // 2048 blocks, 16 lanes per pair

typedef int   v4i __attribute__((ext_vector_type(4)));
typedef float v2f __attribute__((ext_vector_type(2)));

// Single fused kernel: varlen + sparse + dense per row-pair, no atomics,
// no output-init dependency, one plain float2 store per pair.
//
// Lane roles within a 16-lane group (one row-pair g -> rows 2g, 2g+1):
//  - all lanes:   4-5 aligned int4 varlen-id loads -> 20 table gathers
//  - lanes 0-9:   one int4 sparse-id chunk (row = 2g+(t>=5), feats 4*(t%5)..+3)
//  - lanes 0-12:  one dense column pair (d0 = x[2g][t], d1 = x[2g+1][t])
//  - butterfly reduce both row accumulators, lane 0 stores float2.
__global__ __launch_bounds__(256, 4) void fused_kernel(
    const int*   __restrict__ sparse_ids,     // [B, 20]
    const int*   __restrict__ varlen_ids,     // [B, 3, 50]
    const float* __restrict__ dense_x,        // [B, 13]
    const float* __restrict__ sparse_tables,  // [20, VOCAB]
    const float* __restrict__ varlen_tables,  // [3, VOCAB]
    const float* __restrict__ dense_w,        // [13]
    float*       __restrict__ out)            // [B]
{
    const int tid = blockIdx.x * blockDim.x + threadIdx.x;
    const int g   = tid >> 4;     // row-pair index
    const int t   = tid & 15;     // lane within 16-lane group

    // ---------- issue all id / dense loads first (nontemporal: streamed once) ----
    const v4i* vptr = (const v4i*)(varlen_ids) + (long)g * 75;
    v4i vid[5];
    #pragma unroll
    for (int k = 0; k < 4; ++k)
        vid[k] = __builtin_nontemporal_load(vptr + t + 16 * k);   // chunks 0..63
    v4i zero4 = {0, 0, 0, 0};
    vid[4] = zero4;
    if (t < 11)                                                   // chunks 64..74
        vid[4] = __builtin_nontemporal_load(vptr + t + 64);

    v4i sid = zero4;
    const bool sp = (t < 10);
    if (sp)
        sid = __builtin_nontemporal_load(
                  (const v4i*)(sparse_ids) + (long)(2 * g + (t >= 5)) * 5 + (t % 5));

    const float* dx = dense_x + (long)(2 * g) * N_DENSE;          // 26 floats/pair
    float d0 = 0.f, d1 = 0.f, wt = 0.f;
    if (t < 13) {
        d0 = __builtin_nontemporal_load(dx + t);                  // row 2g
        d1 = __builtin_nontemporal_load(dx + 13 + t);             // row 2g+1
        wt = dense_w[t];
    }

    // ---------- sparse gathers (deepest latency: 8 MB table, L3) — issue early ---
    float sv0 = 0.f, sv1 = 0.f, sv2 = 0.f, sv3 = 0.f;
    if (sp) {
        const int f0 = 4 * (t % 5);
        sv0 = sparse_tables[(long)(f0 + 0) * VOCAB + sid[0]];
        sv1 = sparse_tables[(long)(f0 + 1) * VOCAB + sid[1]];
        sv2 = sparse_tables[(long)(f0 + 2) * VOCAB + sid[2]];
        sv3 = sparse_tables[(long)(f0 + 3) * VOCAB + sid[3]];
    }

    // ---------- varlen gathers, fully batched into registers ----------------------
    // Lanes t>=11 gather id 0 for k=4 (same broadcast line, masked to 0 below).
    float vv[20];
    #pragma unroll
    for (int k = 0; k < 5; ++k) {
        const int c = (k < 4) ? (t + 16 * k) : (t + 64);          // int4 chunk id
        #pragma unroll
        for (int j = 0; j < 4; ++j) {
            const int s = 4 * c + j;                              // pair-position
            const int p = (s >= VAR_TOT) ? (s - VAR_TOT) : s;     // pos within row
            const int v = (p >= 2 * SEQ_LEN) ? 2 : ((p >= SEQ_LEN) ? 1 : 0);
            vv[4 * k + j] = varlen_tables[(long)v * VOCAB + vid[k][j]];
        }
    }

    // ---------- accumulate ---------------------------------------------------------
    float acc0 = d0 * wt;    // row 2g
    float acc1 = d1 * wt;    // row 2g+1
    #pragma unroll
    for (int k = 0; k < 5; ++k) {
        const int c = (k < 4) ? (t + 16 * k) : (t + 64);
        #pragma unroll
        for (int j = 0; j < 4; ++j) {
            const int  s  = 4 * c + j;
            const bool r1 = (s >= VAR_TOT);
            const float m = (vid[k][j] != 0) ? vv[4 * k + j] : 0.f;
            acc0 += r1 ? 0.f : m;
            acc1 += r1 ? m   : 0.f;
        }
    }
    const float ssum = sv0 + sv1 + sv2 + sv3;   // 0 for lanes >= 10
    acc0 += (t < 5)  ? ssum : 0.f;              // lanes 0-4 -> row 2g
    acc1 += (t >= 5) ? ssum : 0.f;              // lanes 5-9 -> row 2g+1 (10-15 add 0)

    // ---------- 16-lane butterfly, single float2 store per pair --------------------
    #pragma unroll
    for (int o = 1; o < 16; o <<= 1) {
        acc0 += __shfl_xor(acc0, o);
        acc1 += __shfl_xor(acc1, o);
    }
    if (t == 0) {
        v2f r;
        r[0] = acc0;
        r[1] = acc1;
        __builtin_nontemporal_store(r, (v2f*)(out + 2 * g));
    }
}

extern "C" void kernel_launch(void* const* d_in, const int* in_sizes, int n_in,
                              void* d_out, int out_size, void* d_ws, size_t ws_size,
                              hipStream_t stream) {
    const int*   sparse_ids    = (const int*)d_in[0];
    const int*   varlen_ids    = (const int*)d_in[1];
    const float* dense_x       = (const float*)d_in[2];
    const float* sparse_tables = (const float*)d_in[3];
    const float* varlen_tables = (const float*)d_in[4];
    const float* dense_w       = (const float*)d_in[5];
    float*       out           = (float*)d_out;

    fused_kernel<<<NBLK, 256, 0, stream>>>(
        sparse_ids, varlen_ids, dense_x, sparse_tables, varlen_tables, dense_w, out);
}

// Round 6
// 139.402 us; speedup vs baseline: 1.0202x; 1.0202x over previous
//
#include <hip/hip_runtime.h>

// Problem constants (match reference)
constexpr int B        = 65536;
constexpr int N_SPARSE = 20;
constexpr int N_VARLEN = 3;
constexpr int SEQ_LEN  = 50;
constexpr int VOCAB    = 100000;
constexpr int N_DENSE  = 13;
constexpr int VAR_TOT  = N_VARLEN * SEQ_LEN;   // 150

constexpr int NPAIR = B / 2;                   // 32768 row-pairs
constexpr int NBLK  = NPAIR * 16 / 256;        // 2048 blocks, 16 lanes per pair

typedef int   v4i __attribute__((ext_vector_type(4)));
typedef float v2f __attribute__((ext_vector_type(2)));

// Single fused kernel: varlen + sparse + dense per row-pair, no atomics.
// NOTE: plain (cached) loads everywhere. Round-5 evidence: nontemporal id/dense
// loads added +24 MB HBM re-fetch (84.4 vs 60 MB baseline) because varlen rows
// (1200 B) and dense rows (104 B/pair) straddle 128-B lines shared between
// load instructions; nt's no-allocate policy turned those shared-line hits
// into repeat HBM fetches on the gather critical path.
//
// Lane roles within a 16-lane group (one row-pair g -> rows 2g, 2g+1):
//  - all lanes:   4 aligned int4 varlen-id loads; lanes 0-10 a 5th (chunks 64-74)
//  - lanes 0-9:   one int4 sparse-id chunk (row = 2g+(t>=5), feats 4*(t%5)..+3)
//  - lanes 0-12:  one dense column pair (d0 = x[2g][t], d1 = x[2g+1][t])
//  - butterfly reduce both row accumulators, lane 0 stores float2.
__global__ __launch_bounds__(256, 4) void fused_kernel(
    const int*   __restrict__ sparse_ids,     // [B, 20]
    const int*   __restrict__ varlen_ids,     // [B, 3, 50]
    const float* __restrict__ dense_x,        // [B, 13]
    const float* __restrict__ sparse_tables,  // [20, VOCAB]
    const float* __restrict__ varlen_tables,  // [3, VOCAB]
    const float* __restrict__ dense_w,        // [13]
    float*       __restrict__ out)            // [B]
{
    const int tid = blockIdx.x * blockDim.x + threadIdx.x;
    const int g   = tid >> 4;     // row-pair index
    const int t   = tid & 15;     // lane within 16-lane group

    // ---------- issue all id / dense loads first (plain, cached) -----------------
    const v4i* vptr = (const v4i*)(varlen_ids) + (long)g * 75;
    v4i vid[5];
    #pragma unroll
    for (int k = 0; k < 4; ++k) vid[k] = vptr[t + 16 * k];        // chunks 0..63
    const v4i zero4 = {0, 0, 0, 0};
    const bool v5 = (t < 11);                                     // chunks 64..74
    vid[4] = v5 ? vptr[t + 64] : zero4;

    v4i sid = zero4;
    const bool sp = (t < 10);
    if (sp)
        sid = ((const v4i*)sparse_ids)[(long)(2 * g + (t >= 5)) * 5 + (t % 5)];

    const float* dx = dense_x + (long)(2 * g) * N_DENSE;          // 26 floats/pair
    float d0 = 0.f, d1 = 0.f, wt = 0.f;
    if (t < 13) {
        d0 = dx[t];                                               // row 2g
        d1 = dx[13 + t];                                          // row 2g+1
        wt = dense_w[t];
    }

    // ---------- sparse gathers (deepest latency: 8 MB table) — issue early -------
    float sv0 = 0.f, sv1 = 0.f, sv2 = 0.f, sv3 = 0.f;
    if (sp) {
        const int f0 = 4 * (t % 5);
        sv0 = sparse_tables[(long)(f0 + 0) * VOCAB + sid[0]];
        sv1 = sparse_tables[(long)(f0 + 1) * VOCAB + sid[1]];
        sv2 = sparse_tables[(long)(f0 + 2) * VOCAB + sid[2]];
        sv3 = sparse_tables[(long)(f0 + 3) * VOCAB + sid[3]];
    }

    // ---------- varlen gathers, fully batched into registers ----------------------
    // k=4 is exec-masked to lanes t<11: the t>=11 dummy gathers cost ~20 wasted
    // TA address slots per wave in the previous version.
    float vv[20];
    #pragma unroll
    for (int k = 0; k < 4; ++k) {
        const int c = t + 16 * k;
        #pragma unroll
        for (int j = 0; j < 4; ++j) {
            const int s = 4 * c + j;                              // pair-position
            const int p = (s >= VAR_TOT) ? (s - VAR_TOT) : s;     // pos within row
            const int v = (p >= 2 * SEQ_LEN) ? 2 : ((p >= SEQ_LEN) ? 1 : 0);
            vv[4 * k + j] = varlen_tables[(long)v * VOCAB + vid[k][j]];
        }
    }
    vv[16] = vv[17] = vv[18] = vv[19] = 0.f;
    if (v5) {
        const int c = t + 64;                                     // chunks 64..74
        #pragma unroll
        for (int j = 0; j < 4; ++j) {
            const int s = 4 * c + j;                              // 256..299
            const int p = (s >= VAR_TOT) ? (s - VAR_TOT) : s;
            const int v = (p >= 2 * SEQ_LEN) ? 2 : ((p >= SEQ_LEN) ? 1 : 0);
            vv[16 + j] = varlen_tables[(long)v * VOCAB + vid[4][j]];
        }
    }

    // ---------- accumulate ---------------------------------------------------------
    float acc0 = d0 * wt;    // row 2g
    float acc1 = d1 * wt;    // row 2g+1
    #pragma unroll
    for (int k = 0; k < 5; ++k) {
        const int c = (k < 4) ? (t + 16 * k) : (t + 64);
        #pragma unroll
        for (int j = 0; j < 4; ++j) {
            const int  s  = 4 * c + j;
            const bool r1 = (s >= VAR_TOT);
            // vid[4]==0 for t>=11 -> m==0, so the masked-off k=4 lanes add 0.
            const float m = (vid[k][j] != 0) ? vv[4 * k + j] : 0.f;
            acc0 += r1 ? 0.f : m;
            acc1 += r1 ? m   : 0.f;
        }
    }
    const float ssum = sv0 + sv1 + sv2 + sv3;   // 0 for lanes >= 10
    acc0 += (t < 5)  ? ssum : 0.f;              // lanes 0-4 -> row 2g
    acc1 += (t >= 5) ? ssum : 0.f;              // lanes 5-9 -> row 2g+1 (10-15 add 0)

    // ---------- 16-lane butterfly, single float2 store per pair --------------------
    #pragma unroll
    for (int o = 1; o < 16; o <<= 1) {
        acc0 += __shfl_xor(acc0, o);
        acc1 += __shfl_xor(acc1, o);
    }
    if (t == 0) {
        v2f r;
        r[0] = acc0;
        r[1] = acc1;
        __builtin_nontemporal_store(r, (v2f*)(out + 2 * g));
    }
}

extern "C" void kernel_launch(void* const* d_in, const int* in_sizes, int n_in,
                              void* d_out, int out_size, void* d_ws, size_t ws_size,
                              hipStream_t stream) {
    const int*   sparse_ids    = (const int*)d_in[0];
    const int*   varlen_ids    = (const int*)d_in[1];
    const float* dense_x       = (const float*)d_in[2];
    const float* sparse_tables = (const float*)d_in[3];
    const float* varlen_tables = (const float*)d_in[4];
    const float* dense_w       = (const float*)d_in[5];
    float*       out           = (float*)d_out;

    fused_kernel<<<NBLK, 256, 0, stream>>>(
        sparse_ids, varlen_ids, dense_x, sparse_tables, varlen_tables, dense_w, out);
}